// Round 1
// baseline (99.509 us; speedup 1.0000x reference)
//
#include <hip/hip_runtime.h>

#define NFILT 80
#define NBINS 257          // 512/2 + 1
#define NPTS  (NFILT + 2)  // 82 binpoints
#define NTRI  (NFILT - 1)  // 79 triangular rows (row 79 of fbank is zeros)
#define ROWS_PER_BLOCK 16
#define BLOCK 256

// Kernel 1: sort binpoints, build per-filter descriptors into ws.
// desc[f*8 + {0..6}] = { bj, bj2, inv_d_rise, inv_d_fall, lj, lj1, lj2 }
__global__ void build_desc_kernel(const float* __restrict__ bp,
                                  float* __restrict__ desc) {
    __shared__ float b[NPTS];
    int tid = threadIdx.x;
    if (tid == 0) {
        float tmp[NPTS];
        for (int i = 0; i < NPTS; ++i) tmp[i] = bp[i];
        // insertion sort (82 elems, single thread, negligible)
        for (int i = 1; i < NPTS; ++i) {
            float v = tmp[i];
            int j = i - 1;
            while (j >= 0 && tmp[j] > v) { tmp[j + 1] = tmp[j]; --j; }
            tmp[j + 1] = v;
        }
        for (int i = 0; i < NPTS; ++i) b[i] = tmp[i];
    }
    __syncthreads();
    if (tid < NTRI) {
        float bj  = b[tid];
        float bj1 = b[tid + 1];
        float bj2 = b[tid + 2];
        float lj  = floorf(bj);
        float lj1 = floorf(bj1);
        float lj2 = floorf(bj2);
        float dr = (bj1 - bj) * (bj1 - bj);
        float df = (bj2 - bj1) * (bj2 - bj1);
        float invr = (dr == 0.0f) ? 1.0f : 1.0f / dr;
        float invf = (df == 0.0f) ? 1.0f : 1.0f / df;
        float* d = desc + tid * 8;
        d[0] = bj;  d[1] = bj2; d[2] = invr; d[3] = invf;
        d[4] = lj;  d[5] = lj1; d[6] = lj2;  d[7] = 0.0f;
    }
}

// Kernel 2: stage ROWS_PER_BLOCK rows of x in LDS (coalesced), then each
// thread computes outputs o = r*80 + f via a short sparse gather.
__global__ __launch_bounds__(BLOCK) void filter_apply_kernel(
        const float* __restrict__ x, const float* __restrict__ desc,
        float* __restrict__ out, int nrows) {
    __shared__ float sx[ROWS_PER_BLOCK * NBINS];  // 16*257*4 = 16448 B
    __shared__ float sd[NTRI * 8];                // 2528 B

    const int tid  = threadIdx.x;
    const int row0 = blockIdx.x * ROWS_PER_BLOCK;
    const int rows = min(ROWS_PER_BLOCK, nrows - row0);
    if (rows <= 0) return;

    for (int i = tid; i < NTRI * 8; i += BLOCK) sd[i] = desc[i];

    const float* xbase = x + (size_t)row0 * NBINS;
    const int nload = rows * NBINS;
    for (int i = tid; i < nload; i += BLOCK) sx[i] = xbase[i];
    __syncthreads();

    float* obase = out + (size_t)row0 * NFILT;
    const int nout = rows * NFILT;
    for (int o = tid; o < nout; o += BLOCK) {
        int r = o / NFILT;
        int f = o - r * NFILT;
        const float* xr = sx + r * NBINS;
        float val;
        if (f == 0) {
            val = xr[0];                 // filtered[:,:,0] = x[:,:,0]
        } else if (f == NFILT - 1) {
            val = 0.0f;                  // fbank row 79 is all zeros
        } else {
            const float* d = sd + f * 8;
            const float bj   = d[0];
            const float bj2  = d[1];
            const float invr = d[2];
            const float invf = d[3];
            const int lj  = (int)d[4];
            const int lj1 = (int)d[5];
            const int lj2 = (int)d[6];
            float acc = 0.0f;
            for (int k = lj; k < lj1; ++k)
                acc += xr[k] * (((float)k - bj) * invr);
            for (int k = lj1; k < lj2; ++k)
                acc += xr[k] * ((bj2 - (float)k) * invf);
            val = acc;
        }
        obase[o] = val;
    }
}

extern "C" void kernel_launch(void* const* d_in, const int* in_sizes, int n_in,
                              void* d_out, int out_size, void* d_ws, size_t ws_size,
                              hipStream_t stream) {
    const float* x  = (const float*)d_in[0];
    const float* bp = (const float*)d_in[1];
    float* out  = (float*)d_out;
    float* desc = (float*)d_ws;  // needs 79*8*4 = 2528 bytes

    const int nrows = in_sizes[0] / NBINS;  // 32*4096 = 131072

    build_desc_kernel<<<1, 128, 0, stream>>>(bp, desc);

    const int grid = (nrows + ROWS_PER_BLOCK - 1) / ROWS_PER_BLOCK;
    filter_apply_kernel<<<grid, BLOCK, 0, stream>>>(x, desc, out, nrows);
}